// Round 5
// baseline (176.506 us; speedup 1.0000x reference)
//
#include <hip/hip_runtime.h>
#include <math.h>

#define NUM_EXPERTS 64
#define TOP_K 6
#define HIDDEN 2048
#define INTER 1024
#define NBLK 256
#define NTHR 512
#define ROWS_PER_BLK (TOP_K * INTER / NBLK)   // 24
#define GEN_STEP 0x9E3779B9u

// ws layout (dword units):
//   [0]        gen      (monotone generation counter; ANY initial value works)
//   [64..319]  flags[256] (per-block arrival flags; fresh target each barrier)
//   [320..383] logits[64]
//   [512..6655] hbuf[6144]

// Generation-based grid barrier: no counter reset needed, works with arbitrary
// initial ws content (targets gen+C, gen+2C are never at-rest values).
// Release/acquire at AGENT scope for cross-XCD coherence.
__device__ __forceinline__ void grid_barrier(unsigned* gen, unsigned* flags,
                                             unsigned target, int b, int t) {
    __threadfence();                        // each thread's prior global writes
    __syncthreads();
    if (t == 0)
        __hip_atomic_store(&flags[b], target, __ATOMIC_RELEASE, __HIP_MEMORY_SCOPE_AGENT);
    if (b == 0) {
        if (t < NBLK) {
            while (__hip_atomic_load(&flags[t], __ATOMIC_ACQUIRE, __HIP_MEMORY_SCOPE_AGENT) != target)
                __builtin_amdgcn_s_sleep(1);
        }
        __syncthreads();
        if (t == 0) {
            __threadfence();
            __hip_atomic_store(gen, target, __ATOMIC_RELEASE, __HIP_MEMORY_SCOPE_AGENT);
        }
    }
    if (t == 0) {
        while (__hip_atomic_load(gen, __ATOMIC_ACQUIRE, __HIP_MEMORY_SCOPE_AGENT) != target)
            __builtin_amdgcn_s_sleep(1);
        __threadfence();
    }
    __syncthreads();
}

__global__ __launch_bounds__(NTHR) void k_moe(const float* __restrict__ gw,
                                              const float* __restrict__ x,
                                              const float* __restrict__ bias,
                                              const float* __restrict__ w1,
                                              const float* __restrict__ w2,
                                              const float* __restrict__ w3,
                                              unsigned* __restrict__ wsu,
                                              float* __restrict__ out) {
    unsigned* gen   = wsu;
    unsigned* flags = wsu + 64;
    float* logits   = (float*)(wsu + 320);
    float* hbuf     = (float*)(wsu + 512);

    __shared__ float4 xs[HIDDEN / 4];        // 8 KB
    __shared__ float4 hs[TOP_K * INTER / 4]; // 24 KB
    __shared__ float  ls[8];
    __shared__ int    sidx[TOP_K];
    __shared__ float  swgt[TOP_K];

    const int t = threadIdx.x;
    const int b = blockIdx.x;
    const int wave = t >> 6;
    const int lane = t & 63;

    // quiescent gen value — read strictly before this block arrives at barrier 1,
    // and gen is only written after ALL blocks arrive, so all blocks agree.
    unsigned g0 = __hip_atomic_load(gen, __ATOMIC_RELAXED, __HIP_MEMORY_SCOPE_AGENT);

    // ---- phase 0: stage x (512 threads x 1 float4 = 2048 floats) ----
    xs[t] = ((const float4*)x)[t];
    __syncthreads();

    // ---- phase 1: gate logits (blocks 0..63, one expert row each) ----
    if (b < NUM_EXPERTS) {
        const float4* r4 = (const float4*)(gw + (size_t)b * HIDDEN);
        float4 a = r4[t];
        float4 xv = xs[t];
        float sum = a.x * xv.x + a.y * xv.y + a.z * xv.z + a.w * xv.w;
        #pragma unroll
        for (int o = 32; o; o >>= 1) sum += __shfl_down(sum, o, 64);
        if (lane == 0) ls[wave] = sum;
        __syncthreads();
        if (t == 0) {
            float s = 0.f;
            #pragma unroll
            for (int w = 0; w < 8; w++) s += ls[w];
            logits[b] = s;
        }
    }

    grid_barrier(gen, flags, g0 + GEN_STEP, b, t);

    // ---- phase 2: per-block redundant wave-parallel top-6 ----
    if (wave == 0) {
        float lg = logits[lane];                 // lane = expert, 64 lanes
        float sc = 1.0f / (1.0f + expf(-lg));    // unbiased score (gate weight)
        float cur = sc + bias[lane];             // biased score (routing key)

        int i0, i1, i2, i3, i4, i5;
        float s0, s1, s2, s3, s4, s5;

#define ARGMAX_ROUND(IK, SK)                                                   \
        {                                                                      \
            float v = cur; int li = lane;                                      \
            _Pragma("unroll")                                                  \
            for (int o = 32; o; o >>= 1) {                                     \
                float ov = __shfl_down(v, o, 64);                              \
                int   oi = __shfl_down(li, o, 64);                             \
                if (ov > v || (ov == v && oi < li)) { v = ov; li = oi; }       \
            }                                                                  \
            li = __shfl(li, 0, 64);                                            \
            IK = li;                                                           \
            SK = __shfl(sc, li, 64);                                           \
            if (lane == li) cur = -1e30f;                                      \
        }
        ARGMAX_ROUND(i0, s0)
        ARGMAX_ROUND(i1, s1)
        ARGMAX_ROUND(i2, s2)
        ARGMAX_ROUND(i3, s3)
        ARGMAX_ROUND(i4, s4)
        ARGMAX_ROUND(i5, s5)
#undef ARGMAX_ROUND

        float inv = 1.0f / (s0 + s1 + s2 + s3 + s4 + s5 + 1e-20f);  // SCALE=1
        if (lane == 0) {
            sidx[0] = i0; sidx[1] = i1; sidx[2] = i2;
            sidx[3] = i3; sidx[4] = i4; sidx[5] = i5;
            swgt[0] = s0 * inv; swgt[1] = s1 * inv; swgt[2] = s2 * inv;
            swgt[3] = s3 * inv; swgt[4] = s4 * inv; swgt[5] = s5 * inv;
        }
    }
    __syncthreads();

    // ---- phase 3: mlp1 — 24 rows/block, 3 rows/wave, interleaved streams ----
    {
        const int gb = b * ROWS_PER_BLK + wave * 3;
        const int g0r = gb, g1r = gb + 1, g2r = gb + 2;
        const int e0 = sidx[g0r >> 10], e1 = sidx[g1r >> 10], e2 = sidx[g2r >> 10];
        const float4* a0 = (const float4*)(w1 + ((size_t)e0 * INTER + (g0r & 1023)) * HIDDEN);
        const float4* a1 = (const float4*)(w1 + ((size_t)e1 * INTER + (g1r & 1023)) * HIDDEN);
        const float4* a2 = (const float4*)(w1 + ((size_t)e2 * INTER + (g2r & 1023)) * HIDDEN);
        const float4* b0 = (const float4*)(w3 + ((size_t)e0 * INTER + (g0r & 1023)) * HIDDEN);
        const float4* b1 = (const float4*)(w3 + ((size_t)e1 * INTER + (g1r & 1023)) * HIDDEN);
        const float4* b2 = (const float4*)(w3 + ((size_t)e2 * INTER + (g2r & 1023)) * HIDDEN);
        float sg0 = 0.f, sg1 = 0.f, sg2 = 0.f, su0 = 0.f, su1 = 0.f, su2 = 0.f;
        #pragma unroll
        for (int j = 0; j < 8; j++) {
            const int o = lane + 64 * j;
            float4 xv = xs[o];
            float4 A;
            A = a0[o]; sg0 += A.x * xv.x + A.y * xv.y + A.z * xv.z + A.w * xv.w;
            A = b0[o]; su0 += A.x * xv.x + A.y * xv.y + A.z * xv.z + A.w * xv.w;
            A = a1[o]; sg1 += A.x * xv.x + A.y * xv.y + A.z * xv.z + A.w * xv.w;
            A = b1[o]; su1 += A.x * xv.x + A.y * xv.y + A.z * xv.z + A.w * xv.w;
            A = a2[o]; sg2 += A.x * xv.x + A.y * xv.y + A.z * xv.z + A.w * xv.w;
            A = b2[o]; su2 += A.x * xv.x + A.y * xv.y + A.z * xv.z + A.w * xv.w;
        }
        #pragma unroll
        for (int o = 32; o; o >>= 1) {
            sg0 += __shfl_down(sg0, o, 64); su0 += __shfl_down(su0, o, 64);
            sg1 += __shfl_down(sg1, o, 64); su1 += __shfl_down(su1, o, 64);
            sg2 += __shfl_down(sg2, o, 64); su2 += __shfl_down(su2, o, 64);
        }
        if (lane == 0) {
            hbuf[g0r] = (sg0 / (1.0f + expf(-sg0))) * su0;
            hbuf[g1r] = (sg1 / (1.0f + expf(-sg1))) * su1;
            hbuf[g2r] = (sg2 / (1.0f + expf(-sg2))) * su2;
        }
    }

    grid_barrier(gen, flags, g0 + 2 * GEN_STEP, b, t);

    // ---- phase 4: mlp2 — stage hbuf to LDS, one output h per wave ----
    {
        const float4* h4 = (const float4*)hbuf;
        #pragma unroll
        for (int i = t; i < TOP_K * INTER / 4; i += NTHR) hs[i] = h4[i];
        __syncthreads();

        const int h = b * 8 + wave;              // 256*8 = 2048 outputs
        float acc = 0.f;
        #pragma unroll
        for (int k = 0; k < TOP_K; k++) {
            const int e = sidx[k];
            const float4* r4 = (const float4*)(w2 + ((size_t)e * HIDDEN + h) * INTER);
            float s = 0.f;
            #pragma unroll
            for (int j = 0; j < 4; j++) {
                float4 A = r4[lane + 64 * j];
                float4 B = hs[k * (INTER / 4) + lane + 64 * j];
                s += A.x * B.x + A.y * B.y + A.z * B.z + A.w * B.w;
            }
            acc += swgt[k] * s;
        }
        #pragma unroll
        for (int o = 32; o; o >>= 1) acc += __shfl_down(acc, o, 64);
        if (lane == 0) out[h] = acc;
    }
}

extern "C" void kernel_launch(void* const* d_in, const int* in_sizes, int n_in,
                              void* d_out, int out_size, void* d_ws, size_t ws_size,
                              hipStream_t stream) {
    const float* x    = (const float*)d_in[0];
    const float* gw   = (const float*)d_in[1];
    const float* bias = (const float*)d_in[2];
    const float* w1   = (const float*)d_in[3];
    const float* w2   = (const float*)d_in[4];
    const float* w3   = (const float*)d_in[5];
    float* out = (float*)d_out;
    unsigned* wsu = (unsigned*)d_ws;

    k_moe<<<NBLK, NTHR, 0, stream>>>(gw, x, bias, w1, w2, w3, wsu, out);
}

// Round 6
// 41.329 us; speedup vs baseline: 4.2708x; 4.2708x over previous
//
#include <hip/hip_runtime.h>
#include <math.h>

#define NUM_EXPERTS 64
#define TOP_K 6
#define HIDDEN 2048
#define INTER 1024

// ---------------- Kernel 1: routing — gate GEMV + top-6 in ONE block ----------------
// 1024 threads = 16 waves; each wave computes 4 expert logits (512 KB total reads,
// L2/L3-resident on timed replays); wave 0 then runs the wave-parallel top-6.
// No grid sync, no counter init, one dispatch.
__global__ __launch_bounds__(1024) void k_route(const float* __restrict__ gw,
                                                const float* __restrict__ x,
                                                const float* __restrict__ bias,
                                                int* __restrict__ idx,
                                                float* __restrict__ wgt) {
    __shared__ float4 xs[HIDDEN / 4];          // 8 KB
    __shared__ float  lg[NUM_EXPERTS];
    const int t = threadIdx.x;
    const int wave = t >> 6;
    const int lane = t & 63;

    const float4* x4 = (const float4*)x;
    if (t < HIDDEN / 4) xs[t] = x4[t];
    __syncthreads();

    // 16 waves x 4 experts; s[q] indexed only by unrolled q -> registers
    float s[4] = {0.f, 0.f, 0.f, 0.f};
    #pragma unroll
    for (int q = 0; q < 4; q++) {
        const int e = wave * 4 + q;
        const float4* r4 = (const float4*)(gw + (size_t)e * HIDDEN);
        #pragma unroll
        for (int j = 0; j < 8; j++) {
            float4 a = r4[lane + 64 * j];
            float4 xv = xs[lane + 64 * j];
            s[q] += a.x * xv.x + a.y * xv.y + a.z * xv.z + a.w * xv.w;
        }
    }
    #pragma unroll
    for (int o = 32; o; o >>= 1) {
        #pragma unroll
        for (int q = 0; q < 4; q++) s[q] += __shfl_down(s[q], o, 64);
    }
    if (lane == 0) {
        #pragma unroll
        for (int q = 0; q < 4; q++) lg[wave * 4 + q] = s[q];
    }
    __syncthreads();

    if (wave == 0) {                           // 64 lanes = 64 experts
        float l = lg[lane];
        float sc = 1.0f / (1.0f + expf(-l));   // unbiased score (gate weight)
        float cur = sc + bias[lane];           // biased score (routing key)

        int i0, i1, i2, i3, i4, i5;
        float s0, s1, s2, s3, s4, s5;

#define ARGMAX_ROUND(IK, SK)                                                   \
        {                                                                      \
            float v = cur; int li = lane;                                      \
            _Pragma("unroll")                                                  \
            for (int o = 32; o; o >>= 1) {                                     \
                float ov = __shfl_down(v, o, 64);                              \
                int   oi = __shfl_down(li, o, 64);                             \
                if (ov > v || (ov == v && oi < li)) { v = ov; li = oi; }       \
            }                                                                  \
            li = __shfl(li, 0, 64);                                            \
            IK = li;                                                           \
            SK = __shfl(sc, li, 64);                                           \
            if (lane == li) cur = -1e30f;                                      \
        }
        ARGMAX_ROUND(i0, s0)
        ARGMAX_ROUND(i1, s1)
        ARGMAX_ROUND(i2, s2)
        ARGMAX_ROUND(i3, s3)
        ARGMAX_ROUND(i4, s4)
        ARGMAX_ROUND(i5, s5)
#undef ARGMAX_ROUND

        float inv = 1.0f / (s0 + s1 + s2 + s3 + s4 + s5 + 1e-20f);  // SCALE = 1.0
        if (lane == 0) {
            idx[0] = i0; idx[1] = i1; idx[2] = i2; idx[3] = i3; idx[4] = i4; idx[5] = i5;
            wgt[0] = s0 * inv; wgt[1] = s1 * inv; wgt[2] = s2 * inv;
            wgt[3] = s3 * inv; wgt[4] = s4 * inv; wgt[5] = s5 * inv;
        }
    }
}

// ---------------- Kernel 2: h[k][i] = silu(w1[e_k][i].x) * (w3[e_k][i].x) ----------------
// one wave per inter-row; grid = TOP_K*INTER/4 blocks of 256 (4 waves). x staged in LDS.
__global__ __launch_bounds__(256) void k_mlp1(const float* __restrict__ w1,
                                              const float* __restrict__ w3,
                                              const float* __restrict__ x,
                                              const int* __restrict__ idx,
                                              float* __restrict__ hbuf) {
    __shared__ float4 xs[HIDDEN / 4];          // 8 KB
    int t = threadIdx.x;
    const float4* x4 = (const float4*)x;
    #pragma unroll
    for (int i = t; i < HIDDEN / 4; i += 256) xs[i] = x4[i];
    __syncthreads();

    int wave = t >> 6;
    int lane = t & 63;
    int g = blockIdx.x * 4 + wave;             // [0, TOP_K*INTER)
    int k = g >> 10;                           // / INTER
    int i = g & (INTER - 1);
    int e = idx[k];                            // single dependent load

    float4 xr[8];
    #pragma unroll
    for (int j = 0; j < 8; j++) xr[j] = xs[lane + 64 * j];

    const float4* a4 = (const float4*)(w1 + ((size_t)e * INTER + i) * HIDDEN);
    const float4* b4 = (const float4*)(w3 + ((size_t)e * INTER + i) * HIDDEN);
    float sg = 0.f, su = 0.f;
    #pragma unroll
    for (int j = 0; j < 8; j++) {
        float4 a = a4[lane + 64 * j];
        sg += a.x * xr[j].x + a.y * xr[j].y + a.z * xr[j].z + a.w * xr[j].w;
        float4 b = b4[lane + 64 * j];
        su += b.x * xr[j].x + b.y * xr[j].y + b.z * xr[j].z + b.w * xr[j].w;
    }
    #pragma unroll
    for (int o = 32; o; o >>= 1) {
        sg += __shfl_down(sg, o, 64);
        su += __shfl_down(su, o, 64);
    }
    if (lane == 0) {
        float gate = sg / (1.0f + expf(-sg));   // silu
        hbuf[k * INTER + i] = gate * su;
    }
}

// ---------------- Kernel 3: out[h] = sum_k w[k] * dot(w2[e_k][h], h_k) ----------------
// one wave per output element; grid = HIDDEN/4 blocks of 256 (4 waves).
// hbuf (24 KB) + idx/wgt staged in LDS per block.
__global__ __launch_bounds__(256) void k_mlp2(const float* __restrict__ w2,
                                              const int* __restrict__ idx,
                                              const float* __restrict__ wgt,
                                              const float* __restrict__ hbuf,
                                              float* __restrict__ out) {
    __shared__ float4 hs[TOP_K * INTER / 4];   // 24 KB
    __shared__ int   sidx[TOP_K];
    __shared__ float swgt[TOP_K];
    int t = threadIdx.x;
    if (t < TOP_K) { sidx[t] = idx[t]; swgt[t] = wgt[t]; }
    const float4* h4 = (const float4*)hbuf;
    #pragma unroll
    for (int i = t; i < TOP_K * INTER / 4; i += 256) hs[i] = h4[i];
    __syncthreads();

    int wave = t >> 6;
    int lane = t & 63;
    int h = blockIdx.x * 4 + wave;             // [0, HIDDEN)
    float acc = 0.f;
    #pragma unroll
    for (int k = 0; k < TOP_K; k++) {
        int e = sidx[k];
        const float4* r4 = (const float4*)(w2 + ((size_t)e * HIDDEN + h) * INTER);
        float s = 0.f;
        #pragma unroll
        for (int j = 0; j < 4; j++) {
            float4 a = r4[lane + 64 * j];
            float4 b = hs[k * (INTER / 4) + lane + 64 * j];
            s += a.x * b.x + a.y * b.y + a.z * b.z + a.w * b.w;
        }
        acc += swgt[k] * s;
    }
    #pragma unroll
    for (int o = 32; o; o >>= 1) acc += __shfl_down(acc, o, 64);
    if (lane == 0) out[h] = acc;
}

extern "C" void kernel_launch(void* const* d_in, const int* in_sizes, int n_in,
                              void* d_out, int out_size, void* d_ws, size_t ws_size,
                              hipStream_t stream) {
    const float* x    = (const float*)d_in[0];
    const float* gw   = (const float*)d_in[1];
    const float* bias = (const float*)d_in[2];
    const float* w1   = (const float*)d_in[3];
    const float* w2   = (const float*)d_in[4];
    const float* w3   = (const float*)d_in[5];
    float* out = (float*)d_out;

    float* ws_f   = (float*)d_ws;
    int*   idx    = (int*)(ws_f + 64);          // 6 ints
    float* wgt    = ws_f + 72;                  // 6 floats
    float* hbuf   = ws_f + 128;                 // TOP_K*INTER = 6144 floats

    k_route<<<1, 1024, 0, stream>>>(gw, x, bias, idx, wgt);
    k_mlp1<<<TOP_K * INTER / 4, 256, 0, stream>>>(w1, w3, x, idx, hbuf);
    k_mlp2<<<HIDDEN / 4, 256, 0, stream>>>(w2, idx, wgt, hbuf, out);
}

// Round 7
// 40.083 us; speedup vs baseline: 4.4035x; 1.0311x over previous
//
#include <hip/hip_runtime.h>
#include <math.h>

#define NUM_EXPERTS 64
#define TOP_K 6
#define HIDDEN 2048
#define INTER 1024

// ---------------- Kernel 1: routing — gate GEMV + top-6 in ONE block ----------------
__global__ __launch_bounds__(1024) void k_route(const float* __restrict__ gw,
                                                const float* __restrict__ x,
                                                const float* __restrict__ bias,
                                                int* __restrict__ idx,
                                                float* __restrict__ wgt) {
    __shared__ float4 xs[HIDDEN / 4];          // 8 KB
    __shared__ float  lg[NUM_EXPERTS];
    const int t = threadIdx.x;
    const int wave = t >> 6;
    const int lane = t & 63;

    const float4* x4 = (const float4*)x;
    if (t < HIDDEN / 4) xs[t] = x4[t];
    __syncthreads();

    float s[4] = {0.f, 0.f, 0.f, 0.f};
    #pragma unroll
    for (int q = 0; q < 4; q++) {
        const int e = wave * 4 + q;
        const float4* r4 = (const float4*)(gw + (size_t)e * HIDDEN);
        #pragma unroll
        for (int j = 0; j < 8; j++) {
            float4 a = r4[lane + 64 * j];
            float4 xv = xs[lane + 64 * j];
            s[q] += a.x * xv.x + a.y * xv.y + a.z * xv.z + a.w * xv.w;
        }
    }
    #pragma unroll
    for (int o = 32; o; o >>= 1) {
        #pragma unroll
        for (int q = 0; q < 4; q++) s[q] += __shfl_down(s[q], o, 64);
    }
    if (lane == 0) {
        #pragma unroll
        for (int q = 0; q < 4; q++) lg[wave * 4 + q] = s[q];
    }
    __syncthreads();

    if (wave == 0) {                           // 64 lanes = 64 experts
        float l = lg[lane];
        float sc = 1.0f / (1.0f + expf(-l));   // unbiased score (gate weight)
        float cur = sc + bias[lane];           // biased score (routing key)

        int i0, i1, i2, i3, i4, i5;
        float s0, s1, s2, s3, s4, s5;

#define ARGMAX_ROUND(IK, SK)                                                   \
        {                                                                      \
            float v = cur; int li = lane;                                      \
            _Pragma("unroll")                                                  \
            for (int o = 32; o; o >>= 1) {                                     \
                float ov = __shfl_down(v, o, 64);                              \
                int   oi = __shfl_down(li, o, 64);                             \
                if (ov > v || (ov == v && oi < li)) { v = ov; li = oi; }       \
            }                                                                  \
            li = __shfl(li, 0, 64);                                            \
            IK = li;                                                           \
            SK = __shfl(sc, li, 64);                                           \
            if (lane == li) cur = -1e30f;                                      \
        }
        ARGMAX_ROUND(i0, s0)
        ARGMAX_ROUND(i1, s1)
        ARGMAX_ROUND(i2, s2)
        ARGMAX_ROUND(i3, s3)
        ARGMAX_ROUND(i4, s4)
        ARGMAX_ROUND(i5, s5)
#undef ARGMAX_ROUND

        float inv = 1.0f / (s0 + s1 + s2 + s3 + s4 + s5 + 1e-20f);  // SCALE = 1.0
        if (lane == 0) {
            idx[0] = i0; idx[1] = i1; idx[2] = i2; idx[3] = i3; idx[4] = i4; idx[5] = i5;
            wgt[0] = s0 * inv; wgt[1] = s1 * inv; wgt[2] = s2 * inv;
            wgt[3] = s3 * inv; wgt[4] = s4 * inv; wgt[5] = s5 * inv;
        }
    }
}

// ---------------- Kernel 2: h[k][i] = silu(w1.x) * (w3.x) — NO LDS ----------------
// one wave per inter-row; x loaded straight to registers (L1/L2-broadcast-hot).
__global__ __launch_bounds__(256) void k_mlp1(const float* __restrict__ w1,
                                              const float* __restrict__ w3,
                                              const float* __restrict__ x,
                                              const int* __restrict__ idx,
                                              float* __restrict__ hbuf) {
    const int t = threadIdx.x;
    const int wave = t >> 6;
    const int lane = t & 63;
    const int g = blockIdx.x * 4 + wave;       // [0, TOP_K*INTER)
    const int k = g >> 10;                     // / INTER
    const int i = g & (INTER - 1);
    const int e = idx[k];                      // uniform scalar load, issues early

    const float4* x4 = (const float4*)x;
    float4 xr[8];
    #pragma unroll
    for (int j = 0; j < 8; j++) xr[j] = x4[lane + 64 * j];  // independent of idx

    const float4* a4 = (const float4*)(w1 + ((size_t)e * INTER + i) * HIDDEN);
    const float4* b4 = (const float4*)(w3 + ((size_t)e * INTER + i) * HIDDEN);
    float sg = 0.f, su = 0.f;
    #pragma unroll
    for (int j = 0; j < 8; j++) {
        float4 a = a4[lane + 64 * j];
        sg += a.x * xr[j].x + a.y * xr[j].y + a.z * xr[j].z + a.w * xr[j].w;
        float4 b = b4[lane + 64 * j];
        su += b.x * xr[j].x + b.y * xr[j].y + b.z * xr[j].z + b.w * xr[j].w;
    }
    #pragma unroll
    for (int o = 32; o; o >>= 1) {
        sg += __shfl_down(sg, o, 64);
        su += __shfl_down(su, o, 64);
    }
    if (lane == 0) {
        float gate = sg / (1.0f + expf(-sg));   // silu
        hbuf[k * INTER + i] = gate * su;
    }
}

// ---------------- Kernel 3: out[h] = sum_k w[k] * dot(w2[e_k][h], h_k) — NO LDS ----------------
// one wave per output element; hbuf (24 KB) is L2-hot, read per-lane directly.
__global__ __launch_bounds__(256) void k_mlp2(const float* __restrict__ w2,
                                              const int* __restrict__ idx,
                                              const float* __restrict__ wgt,
                                              const float* __restrict__ hbuf,
                                              float* __restrict__ out) {
    const int t = threadIdx.x;
    const int wave = t >> 6;
    const int lane = t & 63;
    const int h = blockIdx.x * 4 + wave;       // [0, HIDDEN)
    const float4* h4 = (const float4*)hbuf;

    float acc = 0.f;
    #pragma unroll
    for (int k = 0; k < TOP_K; k++) {
        const int e = idx[k];                  // uniform scalar loads
        const float w = wgt[k];
        const float4* r4 = (const float4*)(w2 + ((size_t)e * HIDDEN + h) * INTER);
        float s = 0.f;
        #pragma unroll
        for (int j = 0; j < 4; j++) {
            float4 a = r4[lane + 64 * j];
            float4 b = h4[k * (INTER / 4) + lane + 64 * j];
            s += a.x * b.x + a.y * b.y + a.z * b.z + a.w * b.w;
        }
        acc += w * s;
    }
    #pragma unroll
    for (int o = 32; o; o >>= 1) acc += __shfl_down(acc, o, 64);
    if (lane == 0) out[h] = acc;
}

extern "C" void kernel_launch(void* const* d_in, const int* in_sizes, int n_in,
                              void* d_out, int out_size, void* d_ws, size_t ws_size,
                              hipStream_t stream) {
    const float* x    = (const float*)d_in[0];
    const float* gw   = (const float*)d_in[1];
    const float* bias = (const float*)d_in[2];
    const float* w1   = (const float*)d_in[3];
    const float* w2   = (const float*)d_in[4];
    const float* w3   = (const float*)d_in[5];
    float* out = (float*)d_out;

    float* ws_f   = (float*)d_ws;
    int*   idx    = (int*)(ws_f + 64);          // 6 ints
    float* wgt    = ws_f + 72;                  // 6 floats
    float* hbuf   = ws_f + 128;                 // TOP_K*INTER = 6144 floats

    k_route<<<1, 1024, 0, stream>>>(gw, x, bias, idx, wgt);
    k_mlp1<<<TOP_K * INTER / 4, 256, 0, stream>>>(w1, w3, x, idx, hbuf);
    k_mlp2<<<HIDDEN / 4, 256, 0, stream>>>(w2, idx, wgt, hbuf, out);
}

// Round 8
// 39.603 us; speedup vs baseline: 4.4569x; 1.0121x over previous
//
#include <hip/hip_runtime.h>
#include <math.h>

#define NUM_EXPERTS 64
#define TOP_K 6
#define HIDDEN 2048
#define INTER 1024

// ---------------- Kernel 1: routing — gate GEMV + top-6 in ONE block ----------------
__global__ __launch_bounds__(1024) void k_route(const float* __restrict__ gw,
                                                const float* __restrict__ x,
                                                const float* __restrict__ bias,
                                                int* __restrict__ idx,
                                                float* __restrict__ wgt) {
    __shared__ float4 xs[HIDDEN / 4];          // 8 KB
    __shared__ float  lg[NUM_EXPERTS];
    const int t = threadIdx.x;
    const int wave = t >> 6;
    const int lane = t & 63;

    const float4* x4 = (const float4*)x;
    if (t < HIDDEN / 4) xs[t] = x4[t];
    __syncthreads();

    float s[4] = {0.f, 0.f, 0.f, 0.f};
    #pragma unroll
    for (int q = 0; q < 4; q++) {
        const int e = wave * 4 + q;
        const float4* r4 = (const float4*)(gw + (size_t)e * HIDDEN);
        #pragma unroll
        for (int j = 0; j < 8; j++) {
            float4 a = r4[lane + 64 * j];
            float4 xv = xs[lane + 64 * j];
            s[q] += a.x * xv.x + a.y * xv.y + a.z * xv.z + a.w * xv.w;
        }
    }
    #pragma unroll
    for (int o = 32; o; o >>= 1) {
        #pragma unroll
        for (int q = 0; q < 4; q++) s[q] += __shfl_down(s[q], o, 64);
    }
    if (lane == 0) {
        #pragma unroll
        for (int q = 0; q < 4; q++) lg[wave * 4 + q] = s[q];
    }
    __syncthreads();

    if (wave == 0) {                           // 64 lanes = 64 experts
        float l = lg[lane];
        float sc = 1.0f / (1.0f + expf(-l));   // unbiased score (gate weight)
        float cur = sc + bias[lane];           // biased score (routing key)

        int i0, i1, i2, i3, i4, i5;
        float s0, s1, s2, s3, s4, s5;

#define ARGMAX_ROUND(IK, SK)                                                   \
        {                                                                      \
            float v = cur; int li = lane;                                      \
            _Pragma("unroll")                                                  \
            for (int o = 32; o; o >>= 1) {                                     \
                float ov = __shfl_down(v, o, 64);                              \
                int   oi = __shfl_down(li, o, 64);                             \
                if (ov > v || (ov == v && oi < li)) { v = ov; li = oi; }       \
            }                                                                  \
            li = __shfl(li, 0, 64);                                            \
            IK = li;                                                           \
            SK = __shfl(sc, li, 64);                                           \
            if (lane == li) cur = -1e30f;                                      \
        }
        ARGMAX_ROUND(i0, s0)
        ARGMAX_ROUND(i1, s1)
        ARGMAX_ROUND(i2, s2)
        ARGMAX_ROUND(i3, s3)
        ARGMAX_ROUND(i4, s4)
        ARGMAX_ROUND(i5, s5)
#undef ARGMAX_ROUND

        float inv = 1.0f / (s0 + s1 + s2 + s3 + s4 + s5 + 1e-20f);  // SCALE = 1.0
        if (lane == 0) {
            idx[0] = i0; idx[1] = i1; idx[2] = i2; idx[3] = i3; idx[4] = i4; idx[5] = i5;
            wgt[0] = s0 * inv; wgt[1] = s1 * inv; wgt[2] = s2 * inv;
            wgt[3] = s3 * inv; wgt[4] = s4 * inv; wgt[5] = s5 * inv;
        }
    }
}

// ---------------- Kernel 2: h[k][i] = silu(w1.x) * (w3.x) — 512-thr blocks ----------------
// one wave per inter-row; 768 blocks x 8 waves. x loaded straight to registers.
__global__ __launch_bounds__(512) void k_mlp1(const float* __restrict__ w1,
                                              const float* __restrict__ w3,
                                              const float* __restrict__ x,
                                              const int* __restrict__ idx,
                                              float* __restrict__ hbuf) {
    const int t = threadIdx.x;
    const int wave = t >> 6;
    const int lane = t & 63;
    const int g = blockIdx.x * 8 + wave;       // [0, TOP_K*INTER)
    const int k = g >> 10;                     // / INTER
    const int i = g & (INTER - 1);
    const int e = idx[k];                      // wave-uniform load, issues early

    const float4* x4 = (const float4*)x;
    float4 xr[8];
    #pragma unroll
    for (int j = 0; j < 8; j++) xr[j] = x4[lane + 64 * j];  // independent of idx

    const float4* a4 = (const float4*)(w1 + ((size_t)e * INTER + i) * HIDDEN);
    const float4* b4 = (const float4*)(w3 + ((size_t)e * INTER + i) * HIDDEN);
    float sg = 0.f, su = 0.f;
    #pragma unroll
    for (int j = 0; j < 8; j++) {
        float4 a = a4[lane + 64 * j];
        sg += a.x * xr[j].x + a.y * xr[j].y + a.z * xr[j].z + a.w * xr[j].w;
        float4 b = b4[lane + 64 * j];
        su += b.x * xr[j].x + b.y * xr[j].y + b.z * xr[j].z + b.w * xr[j].w;
    }
    #pragma unroll
    for (int o = 32; o; o >>= 1) {
        sg += __shfl_down(sg, o, 64);
        su += __shfl_down(su, o, 64);
    }
    if (lane == 0) {
        float gate = sg / (1.0f + expf(-sg));   // silu
        hbuf[k * INTER + i] = gate * su;
    }
}

// ---------------- Kernel 3: out[h] = sum_k w[k]*dot(w2[e_k][h], h_k) — 512-thr blocks ----------------
// one wave per output h; 256 blocks x 8 waves. idx/wgt hoisted into registers
// before the k-loop so all 6 expert base addresses resolve at kernel start.
__global__ __launch_bounds__(512) void k_mlp2(const float* __restrict__ w2,
                                              const int* __restrict__ idx,
                                              const float* __restrict__ wgt,
                                              const float* __restrict__ hbuf,
                                              float* __restrict__ out) {
    const int t = threadIdx.x;
    const int wave = t >> 6;
    const int lane = t & 63;
    const int h = blockIdx.x * 8 + wave;       // [0, HIDDEN)
    const float4* h4 = (const float4*)hbuf;

    // hoist routing data: 12 independent loads issued up front
    int e[TOP_K]; float w[TOP_K];
    #pragma unroll
    for (int k = 0; k < TOP_K; k++) { e[k] = idx[k]; w[k] = wgt[k]; }

    float acc = 0.f;
    #pragma unroll
    for (int k = 0; k < TOP_K; k++) {
        const float4* r4 = (const float4*)(w2 + ((size_t)e[k] * HIDDEN + h) * INTER);
        float s = 0.f;
        #pragma unroll
        for (int j = 0; j < 4; j++) {
            float4 a = r4[lane + 64 * j];
            float4 b = h4[k * (INTER / 4) + lane + 64 * j];
            s += a.x * b.x + a.y * b.y + a.z * b.z + a.w * b.w;
        }
        acc += w[k] * s;
    }
    #pragma unroll
    for (int o = 32; o; o >>= 1) acc += __shfl_down(acc, o, 64);
    if (lane == 0) out[h] = acc;
}

extern "C" void kernel_launch(void* const* d_in, const int* in_sizes, int n_in,
                              void* d_out, int out_size, void* d_ws, size_t ws_size,
                              hipStream_t stream) {
    const float* x    = (const float*)d_in[0];
    const float* gw   = (const float*)d_in[1];
    const float* bias = (const float*)d_in[2];
    const float* w1   = (const float*)d_in[3];
    const float* w2   = (const float*)d_in[4];
    const float* w3   = (const float*)d_in[5];
    float* out = (float*)d_out;

    float* ws_f   = (float*)d_ws;
    int*   idx    = (int*)(ws_f + 64);          // 6 ints
    float* wgt    = ws_f + 72;                  // 6 floats
    float* hbuf   = ws_f + 128;                 // TOP_K*INTER = 6144 floats

    k_route<<<1, 1024, 0, stream>>>(gw, x, bias, idx, wgt);
    k_mlp1<<<TOP_K * INTER / 8, 512, 0, stream>>>(w1, w3, x, idx, hbuf);
    k_mlp2<<<HIDDEN / 8, 512, 0, stream>>>(w2, idx, wgt, hbuf, out);
}